// Round 1
// baseline (1368.186 us; speedup 1.0000x reference)
//
#include <hip/hip_runtime.h>
#include <math.h>

// ---------------------------------------------------------------------------
// CenMoERewardModel: B=1024, Na=32, D=128 (z96+a32), E=8 experts, top-2,
// N_HEADS=4 (hd=32), FFN F=1024, head 4096->512->4.
// Outputs: r[1024*4] , gates[1024*8] , loss_bal[1]  (f32, concat = 12289)
// ---------------------------------------------------------------------------

#define BATCH 1024
#define NA 32
#define DMODEL 128
#define NEXP 8
#define FFN 1024
#define HH 512

// ---------------- Router: logits, top-2 gates, per-token LSE ----------------
__global__ __launch_bounds__(256) void router_kernel(
    const float* __restrict__ z, const float* __restrict__ a,
    const float* __restrict__ wg,
    float* __restrict__ gates_out, float* __restrict__ lse_ws,
    int* __restrict__ topi, float* __restrict__ topg)
{
    __shared__ float red[256][9];
    const int b = blockIdx.x, t = threadIdx.x;
    float acc[8];
#pragma unroll
    for (int e = 0; e < 8; ++e) acc[e] = 0.f;
#pragma unroll
    for (int i = 0; i < 16; ++i) {
        int f = i * 256 + t;            // 0..4095, coalesced
        int n = f >> 7, d = f & 127;
        float xv = (d < 96) ? z[(b * NA + n) * 96 + d]
                            : a[(b * NA + n) * 32 + d - 96];
        const float* wr = wg + f * 8;
#pragma unroll
        for (int e = 0; e < 8; ++e) acc[e] += xv * wr[e];
    }
#pragma unroll
    for (int e = 0; e < 8; ++e) red[t][e] = acc[e];
    __syncthreads();
    for (int s = 128; s; s >>= 1) {
        if (t < s) {
#pragma unroll
            for (int e = 0; e < 8; ++e) red[t][e] += red[t + s][e];
        }
        __syncthreads();
    }
    if (t == 0) {
        float L[8];
#pragma unroll
        for (int e = 0; e < 8; ++e) L[e] = red[0][e];
        int i0 = 0;
#pragma unroll
        for (int e = 1; e < 8; ++e) if (L[e] > L[i0]) i0 = e;
        int i1 = -1; float v1 = -3.0e38f;
#pragma unroll
        for (int e = 0; e < 8; ++e) if (e != i0 && L[e] > v1) { v1 = L[e]; i1 = e; }
        float e1 = expf(v1 - L[i0]);
        float inv = 1.f / (1.f + e1);
        float g0 = inv, g1 = e1 * inv;
#pragma unroll
        for (int e = 0; e < 8; ++e)
            gates_out[b * 8 + e] = (e == i0) ? g0 : ((e == i1) ? g1 : 0.f);
        float m = L[i0];
        float se = 0.f;
#pragma unroll
        for (int e = 0; e < 8; ++e) se += expf(L[e] - m);
        lse_ws[b] = m + logf(se);
        topi[b * 2 + 0] = i0; topi[b * 2 + 1] = i1;
        topg[b * 2 + 0] = g0; topg[b * 2 + 1] = g1;
    }
}

// ---------------- Balance loss: cv2(importance)+cv2(load)+mean(lse) ---------
__global__ __launch_bounds__(256) void loss_kernel(
    const float* __restrict__ gates, const float* __restrict__ lse,
    float* __restrict__ out_loss)
{
    __shared__ float red[17][256];
    const int t = threadIdx.x;
    float imp[8], ld[8]; float ls = 0.f;
#pragma unroll
    for (int e = 0; e < 8; ++e) { imp[e] = 0.f; ld[e] = 0.f; }
    for (int b = t; b < BATCH; b += 256) {
#pragma unroll
        for (int e = 0; e < 8; ++e) {
            float g = gates[b * 8 + e];
            imp[e] += g;
            ld[e] += (g > 0.f) ? 1.f : 0.f;
        }
        ls += lse[b];
    }
#pragma unroll
    for (int e = 0; e < 8; ++e) { red[e][t] = imp[e]; red[8 + e][t] = ld[e]; }
    red[16][t] = ls;
    __syncthreads();
    for (int s = 128; s; s >>= 1) {
        if (t < s) {
            for (int q = 0; q < 17; ++q) red[q][t] += red[q][t + s];
        }
        __syncthreads();
    }
    if (t == 0) {
        float cv[2];
        for (int p = 0; p < 2; ++p) {
            float sum = 0.f;
            for (int e = 0; e < 8; ++e) sum += red[p * 8 + e][0];
            float mean = sum * (1.f / 8.f);
            float var = 0.f;
            for (int e = 0; e < 8; ++e) {
                float d = red[p * 8 + e][0] - mean;
                var += d * d;
            }
            var *= (1.f / 7.f);
            cv[p] = var / (mean * mean + 1e-10f);
        }
        out_loss[0] = cv[0] + cv[1] + red[16][0] * (1.f / 1024.f);
    }
}

// ---------------- Expert kernel: 1 block per token, top-2 experts -----------
__global__ __launch_bounds__(256) void expert_kernel(
    const float* __restrict__ z, const float* __restrict__ a,
    const float* __restrict__ w_in, const float* __restrict__ b_in,
    const float* __restrict__ w_out, const float* __restrict__ b_out,
    const float* __restrict__ ln1g, const float* __restrict__ ln1b,
    const float* __restrict__ w1, const float* __restrict__ b1,
    const float* __restrict__ w2, const float* __restrict__ b2,
    const float* __restrict__ ln2g, const float* __restrict__ ln2b,
    const int* __restrict__ topi, const float* __restrict__ topg,
    float* __restrict__ y)
{
    __shared__ float xs[4096];     // x (32x128), preserved across both experts
    __shared__ float qbuf[12288];  // qkv (32x384); later h1[0:4096) + stats[4096:4160)
    __shared__ float obuf[4096];   // o -> (x+o) tmp -> f-chunk -> ln2 tmp

    const int b = blockIdx.x, t = threadIdx.x;
    const int dd = t & 127;        // owned column
    const int nb = (t >> 7) * 16;  // owned row block (0 or 16)

    // stage x = concat(z, a)
#pragma unroll
    for (int i = 0; i < 16; ++i) {
        int f = i * 256 + t;
        int n = f >> 7, d = f & 127;
        xs[f] = (d < 96) ? z[(b * NA + n) * 96 + d]
                         : a[(b * NA + n) * 32 + d - 96];
    }

    float yacc[16];
#pragma unroll
    for (int i = 0; i < 16; ++i) yacc[i] = 0.f;

    for (int s = 0; s < 2; ++s) {
        const int e = topi[b * 2 + s];
        const float g = topg[b * 2 + s];
        const float* wi = w_in + e * 384 * 128;
        const float* bi = b_in + e * 384;
        const float* wo = w_out + e * 128 * 128;
        const float* bo = b_out + e * 128;
        const float* g1 = ln1g + e * 128; const float* be1 = ln1b + e * 128;
        const float* W1 = w1 + e * FFN * 128; const float* B1 = b1 + e * FFN;
        const float* W2 = w2 + e * 128 * FFN; const float* B2 = b2 + e * 128;
        const float* g2 = ln2g + e * 128; const float* be2 = ln2b + e * 128;

        __syncthreads();  // xs ready / previous-expert buffers free

        // ---- Phase 1: qkv[n][j] = x @ wi^T + bi
        for (int jb = 0; jb < 3; ++jb) {
            int j = jb * 128 + dd;
            const float* wr = wi + j * 128;
            float acc[16];
#pragma unroll
            for (int i = 0; i < 16; ++i) acc[i] = 0.f;
            for (int k = 0; k < 128; k += 4) {
                float4 w4 = *(const float4*)(wr + k);
#pragma unroll
                for (int i = 0; i < 16; ++i) {
                    float4 x4 = *(const float4*)(xs + (nb + i) * 128 + k);
                    acc[i] += w4.x * x4.x + w4.y * x4.y + w4.z * x4.z + w4.w * x4.w;
                }
            }
            float bj = bi[j];
#pragma unroll
            for (int i = 0; i < 16; ++i)
                qbuf[(nb + i) * 384 + j] = acc[i] + bj;
        }
        __syncthreads();

        // ---- Phase 2: attention (128 threads: one per (head, q-row))
        if (t < 128) {
            const int h = t >> 5, q = t & 31;
            float qr[32];
#pragma unroll
            for (int d4 = 0; d4 < 8; ++d4) {
                float4 v4 = *(const float4*)(qbuf + q * 384 + h * 32 + d4 * 4);
                qr[d4 * 4 + 0] = v4.x; qr[d4 * 4 + 1] = v4.y;
                qr[d4 * 4 + 2] = v4.z; qr[d4 * 4 + 3] = v4.w;
            }
            float sc[32];
            const float scale = 0.17677669529663687f;  // 1/sqrt(32)
#pragma unroll
            for (int kk = 0; kk < 32; ++kk) {
                const float* kr = qbuf + kk * 384 + 128 + h * 32;
                float acc = 0.f;
#pragma unroll
                for (int d4 = 0; d4 < 8; ++d4) {
                    float4 v4 = *(const float4*)(kr + d4 * 4);
                    acc += qr[d4 * 4] * v4.x + qr[d4 * 4 + 1] * v4.y
                         + qr[d4 * 4 + 2] * v4.z + qr[d4 * 4 + 3] * v4.w;
                }
                sc[kk] = acc * scale;
            }
            float m = sc[0];
#pragma unroll
            for (int kk = 1; kk < 32; ++kk) m = fmaxf(m, sc[kk]);
            float ssum = 0.f;
#pragma unroll
            for (int kk = 0; kk < 32; ++kk) { sc[kk] = __expf(sc[kk] - m); ssum += sc[kk]; }
            float inv = 1.f / ssum;
#pragma unroll
            for (int kk = 0; kk < 32; ++kk) sc[kk] *= inv;
#pragma unroll
            for (int d4 = 0; d4 < 8; ++d4) {
                float ax = 0.f, ay = 0.f, az = 0.f, aw = 0.f;
#pragma unroll
                for (int kk = 0; kk < 32; ++kk) {
                    float4 v4 = *(const float4*)(qbuf + kk * 384 + 256 + h * 32 + d4 * 4);
                    float p = sc[kk];
                    ax += p * v4.x; ay += p * v4.y; az += p * v4.z; aw += p * v4.w;
                }
                float4 o4; o4.x = ax; o4.y = ay; o4.z = az; o4.w = aw;
                *(float4*)(obuf + q * 128 + h * 32 + d4 * 4) = o4;
            }
        }
        __syncthreads();

        // ---- Phase 3: proj + residual -> obuf holds (x+o), then LN1 -> qbuf h1
        {
            const float* wr = wo + dd * 128;
            float acc[16];
#pragma unroll
            for (int i = 0; i < 16; ++i) acc[i] = 0.f;
            for (int k = 0; k < 128; k += 4) {
                float4 w4 = *(const float4*)(wr + k);
#pragma unroll
                for (int i = 0; i < 16; ++i) {
                    float4 o4 = *(const float4*)(obuf + (nb + i) * 128 + k);
                    acc[i] += w4.x * o4.x + w4.y * o4.y + w4.z * o4.z + w4.w * o4.w;
                }
            }
            float bv = bo[dd];
            __syncthreads();  // all o reads done before overwrite
#pragma unroll
            for (int i = 0; i < 16; ++i) {
                int n = nb + i;
                obuf[n * 128 + dd] = xs[n * 128 + dd] + acc[i] + bv;
            }
        }
        __syncthreads();
        if (t < 32) {  // LN1 row stats
            float sum = 0.f, sq = 0.f;
            for (int d4 = 0; d4 < 32; ++d4) {
                float4 v4 = *(const float4*)(obuf + t * 128 + d4 * 4);
                sum += v4.x + v4.y + v4.z + v4.w;
                sq += v4.x * v4.x + v4.y * v4.y + v4.z * v4.z + v4.w * v4.w;
            }
            float mu = sum * (1.f / 128.f);
            float var = sq * (1.f / 128.f) - mu * mu;
            qbuf[4096 + t] = mu;
            qbuf[4128 + t] = rsqrtf(var + 1e-5f);
        }
        __syncthreads();
        {
            float gv = g1[dd], bv = be1[dd];
#pragma unroll
            for (int i = 0; i < 16; ++i) {
                int n = nb + i;
                qbuf[n * 128 + dd] =
                    (obuf[n * 128 + dd] - qbuf[4096 + n]) * qbuf[4128 + n] * gv + bv;
            }
        }
        __syncthreads();

        // ---- Phase 4: FFN in 8 chunks of 128 hidden cols
        float f2acc[16];
#pragma unroll
        for (int i = 0; i < 16; ++i) f2acc[i] = 0.f;
        for (int c = 0; c < 8; ++c) {
            int j = c * 128 + dd;
            const float* wr = W1 + j * 128;
            float acc[16];
#pragma unroll
            for (int i = 0; i < 16; ++i) acc[i] = 0.f;
            for (int k = 0; k < 128; k += 4) {
                float4 w4 = *(const float4*)(wr + k);
#pragma unroll
                for (int i = 0; i < 16; ++i) {
                    float4 h4 = *(const float4*)(qbuf + (nb + i) * 128 + k);
                    acc[i] += w4.x * h4.x + w4.y * h4.y + w4.z * h4.z + w4.w * h4.w;
                }
            }
            float bv = B1[j];
            __syncthreads();  // previous chunk's FFN2 reads done
#pragma unroll
            for (int i = 0; i < 16; ++i)
                obuf[(nb + i) * 128 + dd] = fmaxf(acc[i] + bv, 0.f);
            __syncthreads();
            const float* w2r = W2 + dd * FFN + c * 128;
            for (int k = 0; k < 128; k += 4) {
                float4 w4 = *(const float4*)(w2r + k);
#pragma unroll
                for (int i = 0; i < 16; ++i) {
                    float4 f4 = *(const float4*)(obuf + (nb + i) * 128 + k);
                    f2acc[i] += w4.x * f4.x + w4.y * f4.y + w4.z * f4.z + w4.w * f4.w;
                }
            }
        }
        __syncthreads();
        // ---- Phase 5: LN2(h1 + f) , gate-accumulate
        {
            float bv = B2[dd];
#pragma unroll
            for (int i = 0; i < 16; ++i) {
                int n = nb + i;
                obuf[n * 128 + dd] = qbuf[n * 128 + dd] + f2acc[i] + bv;
            }
        }
        __syncthreads();
        if (t < 32) {
            float sum = 0.f, sq = 0.f;
            for (int d4 = 0; d4 < 32; ++d4) {
                float4 v4 = *(const float4*)(obuf + t * 128 + d4 * 4);
                sum += v4.x + v4.y + v4.z + v4.w;
                sq += v4.x * v4.x + v4.y * v4.y + v4.z * v4.z + v4.w * v4.w;
            }
            float mu = sum * (1.f / 128.f);
            float var = sq * (1.f / 128.f) - mu * mu;
            qbuf[4096 + t] = mu;
            qbuf[4128 + t] = rsqrtf(var + 1e-5f);
        }
        __syncthreads();
        {
            float gv = g2[dd], bv = be2[dd];
#pragma unroll
            for (int i = 0; i < 16; ++i) {
                int n = nb + i;
                float val = (obuf[n * 128 + dd] - qbuf[4096 + n]) * qbuf[4128 + n] * gv + bv;
                yacc[i] += g * val;
            }
        }
    }

#pragma unroll
    for (int i = 0; i < 16; ++i)
        y[(b * NA + nb + i) * 128 + dd] = yacc[i];
}

// ---------------- Head part 1: h_act = relu(y_flat @ hw1^T + hb1) -----------
__global__ __launch_bounds__(256) void head1_kernel(
    const float* __restrict__ y, const float* __restrict__ w1,
    const float* __restrict__ b1, float* __restrict__ h_act)
{
    __shared__ float ylds[32 * 256];  // 32 KB chunk of y rows
    const int h0 = blockIdx.x * 64, b0 = blockIdx.y * 32, t = threadIdx.x;
    const int hh = t & 63, bg = t >> 6;
    const int h = h0 + hh;
    const float* wr = w1 + (size_t)h * 4096;
    float acc[8];
#pragma unroll
    for (int i = 0; i < 8; ++i) acc[i] = 0.f;
    for (int kc = 0; kc < 16; ++kc) {
        int k0 = kc * 256;
        __syncthreads();
#pragma unroll
        for (int i = 0; i < 8; ++i) {
            int idx = i * 256 + t;              // 0..2047
            int row = idx >> 6, col = (idx & 63) * 4;
            *(float4*)(ylds + row * 256 + col) =
                *(const float4*)(y + (size_t)(b0 + row) * 4096 + k0 + col);
        }
        __syncthreads();
        for (int k = 0; k < 256; k += 4) {
            float4 w4 = *(const float4*)(wr + k0 + k);
#pragma unroll
            for (int i = 0; i < 8; ++i) {
                float4 y4 = *(const float4*)(ylds + (bg * 8 + i) * 256 + k);
                acc[i] += w4.x * y4.x + w4.y * y4.y + w4.z * y4.z + w4.w * y4.w;
            }
        }
    }
    float bv = b1[h];
#pragma unroll
    for (int i = 0; i < 8; ++i)
        h_act[(size_t)(b0 + bg * 8 + i) * 512 + h] = fmaxf(acc[i] + bv, 0.f);
}

// ---------------- Head part 2: r = h_act @ hw2^T + hb2 ----------------------
__global__ __launch_bounds__(64) void head2_kernel(
    const float* __restrict__ h_act, const float* __restrict__ w2,
    const float* __restrict__ b2, float* __restrict__ r)
{
    const int b = blockIdx.x, t = threadIdx.x;
    float a0 = 0.f, a1 = 0.f, a2 = 0.f, a3 = 0.f;
    for (int h = t; h < 512; h += 64) {
        float hv = h_act[b * 512 + h];
        a0 += hv * w2[h];
        a1 += hv * w2[512 + h];
        a2 += hv * w2[1024 + h];
        a3 += hv * w2[1536 + h];
    }
#pragma unroll
    for (int off = 32; off; off >>= 1) {
        a0 += __shfl_down(a0, off);
        a1 += __shfl_down(a1, off);
        a2 += __shfl_down(a2, off);
        a3 += __shfl_down(a3, off);
    }
    if (t == 0) {
        r[b * 4 + 0] = a0 + b2[0];
        r[b * 4 + 1] = a1 + b2[1];
        r[b * 4 + 2] = a2 + b2[2];
        r[b * 4 + 3] = a3 + b2[3];
    }
}

// ---------------------------------------------------------------------------
extern "C" void kernel_launch(void* const* d_in, const int* in_sizes, int n_in,
                              void* d_out, int out_size, void* d_ws, size_t ws_size,
                              hipStream_t stream) {
    const float* z    = (const float*)d_in[0];
    const float* a    = (const float*)d_in[1];
    const float* wg   = (const float*)d_in[2];
    const float* w_in = (const float*)d_in[3];
    const float* b_in = (const float*)d_in[4];
    const float* w_o  = (const float*)d_in[5];
    const float* b_o  = (const float*)d_in[6];
    const float* l1g  = (const float*)d_in[7];
    const float* l1b  = (const float*)d_in[8];
    const float* w1   = (const float*)d_in[9];
    const float* b1   = (const float*)d_in[10];
    const float* w2   = (const float*)d_in[11];
    const float* b2   = (const float*)d_in[12];
    const float* l2g  = (const float*)d_in[13];
    const float* l2b  = (const float*)d_in[14];
    const float* hw1  = (const float*)d_in[15];
    const float* hb1  = (const float*)d_in[16];
    const float* hw2  = (const float*)d_in[17];
    const float* hb2  = (const float*)d_in[18];

    float* out = (float*)d_out;
    float* r_out     = out;          // 4096
    float* gates_out = out + 4096;   // 8192
    float* loss_out  = out + 12288;  // 1

    float* ws    = (float*)d_ws;
    float* y     = ws;                     // 1024*4096 = 4,194,304 f32
    float* h_act = ws + 4194304;           // 1024*512  =   524,288 f32
    float* lse   = ws + 4718592;           // 1024
    float* topg  = ws + 4719616;           // 2048
    int*   topi  = (int*)(ws + 4721664);   // 2048 ints

    router_kernel<<<1024, 256, 0, stream>>>(z, a, wg, gates_out, lse, topi, topg);
    loss_kernel<<<1, 256, 0, stream>>>(gates_out, lse, loss_out);
    expert_kernel<<<1024, 256, 0, stream>>>(z, a, w_in, b_in, w_o, b_o,
        l1g, l1b, w1, b1, w2, b2, l2g, l2b, topi, topg, y);
    head1_kernel<<<dim3(8, 32), 256, 0, stream>>>(y, hw1, hb1, h_act);
    head2_kernel<<<1024, 64, 0, stream>>>(h_act, hw2, hb2, r_out);
}

// Round 2
// 485.804 us; speedup vs baseline: 2.8163x; 2.8163x over previous
//
#include <hip/hip_runtime.h>
#include <math.h>

// ---------------------------------------------------------------------------
// CenMoERewardModel bf16-MFMA version.
// B=1024, Na=32, D=128, E=8 top-2, heads=4 (hd=32), F=1024, head 4096->512->4.
// ---------------------------------------------------------------------------

typedef short bf16x8 __attribute__((ext_vector_type(8)));
typedef float f32x4 __attribute__((ext_vector_type(4)));
typedef unsigned short u16;

#define MFMA(a, b, c) __builtin_amdgcn_mfma_f32_16x16x32_bf16((a), (b), (c), 0, 0, 0)

__device__ __forceinline__ u16 f2bf(float f) {
    unsigned int u = __float_as_uint(f);
    unsigned int r = u + 0x7FFFu + ((u >> 16) & 1u);
    return (u16)(r >> 16);
}
__device__ __forceinline__ float bf2f(u16 s) {
    return __uint_as_float(((unsigned int)s) << 16);
}

// ---------------- weight f32 -> bf16 conversion -----------------------------
// segments: w_in 393216 | w_out 131072 | w1 1048576 | w2 1048576 | hw1 2097152
__global__ __launch_bounds__(256) void convert_kernel(
    const float* __restrict__ wi, const float* __restrict__ wo,
    const float* __restrict__ w1, const float* __restrict__ w2,
    const float* __restrict__ hw1,
    u16* __restrict__ wiB, u16* __restrict__ woB, u16* __restrict__ w1B,
    u16* __restrict__ w2B, u16* __restrict__ hw1B)
{
    int i4 = blockIdx.x * 256 + threadIdx.x;  // 4608*256 = 1,179,648 exact
    int e = i4 * 4;
    const float* s; u16* d; int off;
    if (e < 393216)       { s = wi;  d = wiB;  off = e; }
    else if (e < 524288)  { s = wo;  d = woB;  off = e - 393216; }
    else if (e < 1572864) { s = w1;  d = w1B;  off = e - 524288; }
    else if (e < 2621440) { s = w2;  d = w2B;  off = e - 1572864; }
    else                  { s = hw1; d = hw1B; off = e - 2621440; }
    float4 v = *(const float4*)(s + off);
    ushort4 o;
    o.x = f2bf(v.x); o.y = f2bf(v.y); o.z = f2bf(v.z); o.w = f2bf(v.w);
    *(ushort4*)(d + off) = o;
}

// ---------------- Router (f32 exact) ---------------------------------------
__global__ __launch_bounds__(256) void router_kernel(
    const float* __restrict__ z, const float* __restrict__ a,
    const float* __restrict__ wg,
    float* __restrict__ gates_out, float* __restrict__ lse_ws,
    int* __restrict__ topi, float* __restrict__ topg)
{
    __shared__ float red[256][9];
    const int b = blockIdx.x, t = threadIdx.x;
    float acc[8];
#pragma unroll
    for (int e = 0; e < 8; ++e) acc[e] = 0.f;
#pragma unroll
    for (int i = 0; i < 16; ++i) {
        int f = i * 256 + t;
        int n = f >> 7, d = f & 127;
        float xv = (d < 96) ? z[(b * 32 + n) * 96 + d]
                            : a[(b * 32 + n) * 32 + d - 96];
        const float* wr = wg + f * 8;
#pragma unroll
        for (int e = 0; e < 8; ++e) acc[e] += xv * wr[e];
    }
#pragma unroll
    for (int e = 0; e < 8; ++e) red[t][e] = acc[e];
    __syncthreads();
    for (int s = 128; s; s >>= 1) {
        if (t < s) {
#pragma unroll
            for (int e = 0; e < 8; ++e) red[t][e] += red[t + s][e];
        }
        __syncthreads();
    }
    if (t == 0) {
        float L[8];
#pragma unroll
        for (int e = 0; e < 8; ++e) L[e] = red[0][e];
        int i0 = 0;
#pragma unroll
        for (int e = 1; e < 8; ++e) if (L[e] > L[i0]) i0 = e;
        int i1 = -1; float v1 = -3.0e38f;
#pragma unroll
        for (int e = 0; e < 8; ++e) if (e != i0 && L[e] > v1) { v1 = L[e]; i1 = e; }
        float e1 = expf(v1 - L[i0]);
        float inv = 1.f / (1.f + e1);
        float g0 = inv, g1 = e1 * inv;
#pragma unroll
        for (int e = 0; e < 8; ++e)
            gates_out[b * 8 + e] = (e == i0) ? g0 : ((e == i1) ? g1 : 0.f);
        float m = L[i0];
        float se = 0.f;
#pragma unroll
        for (int e = 0; e < 8; ++e) se += expf(L[e] - m);
        lse_ws[b] = m + logf(se);
        topi[b * 2 + 0] = i0; topi[b * 2 + 1] = i1;
        topg[b * 2 + 0] = g0; topg[b * 2 + 1] = g1;
    }
}

// ---------------- Balance loss ---------------------------------------------
__global__ __launch_bounds__(256) void loss_kernel(
    const float* __restrict__ gates, const float* __restrict__ lse,
    float* __restrict__ out_loss)
{
    __shared__ float red[17][256];
    const int t = threadIdx.x;
    float imp[8], ld[8]; float ls = 0.f;
#pragma unroll
    for (int e = 0; e < 8; ++e) { imp[e] = 0.f; ld[e] = 0.f; }
    for (int b = t; b < 1024; b += 256) {
#pragma unroll
        for (int e = 0; e < 8; ++e) {
            float g = gates[b * 8 + e];
            imp[e] += g;
            ld[e] += (g > 0.f) ? 1.f : 0.f;
        }
        ls += lse[b];
    }
#pragma unroll
    for (int e = 0; e < 8; ++e) { red[e][t] = imp[e]; red[8 + e][t] = ld[e]; }
    red[16][t] = ls;
    __syncthreads();
    for (int s = 128; s; s >>= 1) {
        if (t < s) {
            for (int q = 0; q < 17; ++q) red[q][t] += red[q][t + s];
        }
        __syncthreads();
    }
    if (t == 0) {
        float cv[2];
        for (int p = 0; p < 2; ++p) {
            float sum = 0.f;
            for (int e = 0; e < 8; ++e) sum += red[p * 8 + e][0];
            float mean = sum * (1.f / 8.f);
            float var = 0.f;
            for (int e = 0; e < 8; ++e) {
                float dd = red[p * 8 + e][0] - mean;
                var += dd * dd;
            }
            var *= (1.f / 7.f);
            cv[p] = var / (mean * mean + 1e-10f);
        }
        out_loss[0] = cv[0] + cv[1] + red[16][0] * (1.f / 1024.f);
    }
}

// ---------------- Expert kernel (bf16 MFMA) --------------------------------
// LDS map (bytes):
//   [0,8192)        xbf  bf16[32][128]  swz8, persistent
//   U = 8192:
//   U+[0,24576)     qkv  bf16[32][384]  swz8 (stride 768)      phase 1-2
//   U+[0,8192)      obf  bf16[32][128]  swz8                   post-attn
//   U+[8192,25088)  hf   f32 [32][132]                         proj out
//   U+[25088,33280) pbuf bf16 per-wave [32][32] swzP (str 64)  attn P
//   U+[33280,41472) h1bf bf16[32][128]  swz8                   LN1 out
//   U+[41472,49664) fch  bf16[32][128]  swz8                   FFN chunk
//   U+[49664,49920) stats f32[64]
//   U+[0,16896)     u2   f32 [32][132]                         pre-LN2
#define LDS_U 8192
#define LDS_TOTAL (8192 + 49920)

__global__ __launch_bounds__(256) void expert_kernel(
    const float* __restrict__ z, const float* __restrict__ a,
    const u16* __restrict__ wiBF, const float* __restrict__ b_in,
    const u16* __restrict__ woBF, const float* __restrict__ b_out,
    const float* __restrict__ ln1g, const float* __restrict__ ln1b,
    const u16* __restrict__ w1BF, const float* __restrict__ b1,
    const u16* __restrict__ w2BF, const float* __restrict__ b2,
    const float* __restrict__ ln2g, const float* __restrict__ ln2b,
    const int* __restrict__ topi, const float* __restrict__ topg,
    u16* __restrict__ y_bf)
{
    __shared__ __align__(16) char sm[LDS_TOTAL];
    const int b = blockIdx.x, t = threadIdx.x;
    const int w = t >> 6, l = t & 63, l16 = l & 15, lk = l >> 4;
    const int ke = lk * 8;                 // k-element base within 32-step
    const int dd = t & 127, nb = (t >> 7) * 16;
    const f32x4 zv = {0.f, 0.f, 0.f, 0.f};

    // stage x -> xbf (swizzled)
#pragma unroll
    for (int i = 0; i < 16; ++i) {
        int f = i * 256 + t;
        int n = f >> 7, d = f & 127;
        float xv = (d < 96) ? z[(b * 32 + n) * 96 + d]
                            : a[(b * 32 + n) * 32 + d - 96];
        *(u16*)(sm + n * 256 + ((d * 2) ^ ((n & 7) << 4))) = f2bf(xv);
    }

    float yacc[16];
#pragma unroll
    for (int i = 0; i < 16; ++i) yacc[i] = 0.f;

    for (int s = 0; s < 2; ++s) {
        const int e = topi[b * 2 + s];
        const float g = topg[b * 2 + s];
        const u16* wi = wiBF + e * 49152;
        const u16* wo = woBF + e * 16384;
        const u16* W1 = w1BF + e * 131072;
        const u16* W2 = w2BF + e * 131072;

        __syncthreads();  // xs staged / previous-expert buffers free

        // ---- Phase 1: qkv = x @ wi^T + bi  (wave w: cols [96w, 96w+96))
        {
            f32x4 acc[6][2];
#pragma unroll
            for (int q = 0; q < 6; ++q) { acc[q][0] = zv; acc[q][1] = zv; }
#pragma unroll
            for (int ks = 0; ks < 4; ++ks) {
                int kb = (ks * 32 + ke) * 2;
                bf16x8 a0 = *(const bf16x8*)(sm + l16 * 256 + (kb ^ ((l16 & 7) << 4)));
                bf16x8 a1 = *(const bf16x8*)(sm + (16 + l16) * 256 + (kb ^ (((16 + l16) & 7) << 4)));
#pragma unroll
                for (int q = 0; q < 6; ++q) {
                    int j = (w * 6 + q) * 16 + l16;
                    bf16x8 bb = *(const bf16x8*)(wi + j * 128 + ks * 32 + ke);
                    acc[q][0] = MFMA(a0, bb, acc[q][0]);
                    acc[q][1] = MFMA(a1, bb, acc[q][1]);
                }
            }
#pragma unroll
            for (int q = 0; q < 6; ++q) {
                int j = (w * 6 + q) * 16 + l16;
                float bj = b_in[e * 384 + j];
#pragma unroll
                for (int mt = 0; mt < 2; ++mt)
#pragma unroll
                    for (int i = 0; i < 4; ++i) {
                        int row = mt * 16 + lk * 4 + i;
                        *(u16*)(sm + LDS_U + row * 768 + ((j * 2) ^ ((row & 7) << 4))) =
                            f2bf(acc[q][mt][i] + bj);
                    }
            }
        }
        __syncthreads();

        // ---- Phase 2: attention, wave w == head w
        f32x4 o[2][2];
        {
            const int hb = w * 32;
            int kb = ke * 2;
            bf16x8 qa0 = *(const bf16x8*)(sm + LDS_U + l16 * 768 + (((hb * 2) + kb) ^ ((l16 & 7) << 4)));
            bf16x8 qa1 = *(const bf16x8*)(sm + LDS_U + (16 + l16) * 768 + (((hb * 2) + kb) ^ (((16 + l16) & 7) << 4)));
            bf16x8 kb0 = *(const bf16x8*)(sm + LDS_U + l16 * 768 + ((256 + hb * 2 + kb) ^ ((l16 & 7) << 4)));
            bf16x8 kb1 = *(const bf16x8*)(sm + LDS_U + (16 + l16) * 768 + ((256 + hb * 2 + kb) ^ (((16 + l16) & 7) << 4)));
            f32x4 sc[2][2];
            sc[0][0] = MFMA(qa0, kb0, zv); sc[0][1] = MFMA(qa0, kb1, zv);
            sc[1][0] = MFMA(qa1, kb0, zv); sc[1][1] = MFMA(qa1, kb1, zv);
            const float scale = 0.17677669529663687f;
#pragma unroll
            for (int mt = 0; mt < 2; ++mt)
#pragma unroll
                for (int i = 0; i < 4; ++i) {
                    float v0 = sc[mt][0][i] * scale, v1 = sc[mt][1][i] * scale;
                    float m = fmaxf(v0, v1);
                    m = fmaxf(m, __shfl_xor(m, 1)); m = fmaxf(m, __shfl_xor(m, 2));
                    m = fmaxf(m, __shfl_xor(m, 4)); m = fmaxf(m, __shfl_xor(m, 8));
                    float e0 = __expf(v0 - m), e1 = __expf(v1 - m);
                    float ssum = e0 + e1;
                    ssum += __shfl_xor(ssum, 1); ssum += __shfl_xor(ssum, 2);
                    ssum += __shfl_xor(ssum, 4); ssum += __shfl_xor(ssum, 8);
                    float inv = 1.f / ssum;
                    int row = mt * 16 + lk * 4 + i;
                    int base = LDS_U + 25088 + w * 2048 + row * 64;
                    int sw = ((row >> 1) & 3) << 4;
                    *(u16*)(sm + base + ((l16 * 2) ^ sw)) = f2bf(e0 * inv);
                    *(u16*)(sm + base + ((32 + l16 * 2) ^ sw)) = f2bf(e1 * inv);
                }
            bf16x8 pa0 = *(const bf16x8*)(sm + LDS_U + 25088 + w * 2048 + l16 * 64 +
                                          ((ke * 2) ^ (((l16 >> 1) & 3) << 4)));
            bf16x8 pa1 = *(const bf16x8*)(sm + LDS_U + 25088 + w * 2048 + (16 + l16) * 64 +
                                          ((ke * 2) ^ ((((16 + l16) >> 1) & 3) << 4)));
            o[0][0] = zv; o[0][1] = zv; o[1][0] = zv; o[1][1] = zv;
#pragma unroll
            for (int nt = 0; nt < 2; ++nt) {
                bf16x8 vb;
#pragma unroll
                for (int i2 = 0; i2 < 8; ++i2) {
                    int kt = ke + i2;  // key token
                    int col = 256 + hb + nt * 16 + l16;
                    vb[i2] = *(const short*)(sm + LDS_U + kt * 768 + ((col * 2) ^ ((kt & 7) << 4)));
                }
                o[0][nt] = MFMA(pa0, vb, o[0][nt]);
                o[1][nt] = MFMA(pa1, vb, o[1][nt]);
            }
        }
        __syncthreads();  // all qkv reads done -> obf may overwrite
        {
            const int hb = w * 32;
#pragma unroll
            for (int mt = 0; mt < 2; ++mt)
#pragma unroll
                for (int nt = 0; nt < 2; ++nt)
#pragma unroll
                    for (int i = 0; i < 4; ++i) {
                        int row = mt * 16 + lk * 4 + i, col = hb + nt * 16 + l16;
                        *(u16*)(sm + LDS_U + row * 256 + ((col * 2) ^ ((row & 7) << 4))) =
                            f2bf(o[mt][nt][i]);
                    }
        }
        __syncthreads();

        // ---- Phase 3: proj + residual -> hf
        {
            const int wcb = w * 32;
            f32x4 pr[2][2];
            pr[0][0] = zv; pr[0][1] = zv; pr[1][0] = zv; pr[1][1] = zv;
#pragma unroll
            for (int ks = 0; ks < 4; ++ks) {
                int kb = (ks * 32 + ke) * 2;
                bf16x8 a0 = *(const bf16x8*)(sm + LDS_U + l16 * 256 + (kb ^ ((l16 & 7) << 4)));
                bf16x8 a1 = *(const bf16x8*)(sm + LDS_U + (16 + l16) * 256 + (kb ^ (((16 + l16) & 7) << 4)));
#pragma unroll
                for (int nt = 0; nt < 2; ++nt) {
                    int j = wcb + nt * 16 + l16;
                    bf16x8 bb = *(const bf16x8*)(wo + j * 128 + ks * 32 + ke);
                    pr[0][nt] = MFMA(a0, bb, pr[0][nt]);
                    pr[1][nt] = MFMA(a1, bb, pr[1][nt]);
                }
            }
#pragma unroll
            for (int nt = 0; nt < 2; ++nt) {
                int col = wcb + nt * 16 + l16;
                float bv = b_out[e * 128 + col];
#pragma unroll
                for (int mt = 0; mt < 2; ++mt)
#pragma unroll
                    for (int i = 0; i < 4; ++i) {
                        int row = mt * 16 + lk * 4 + i;
                        float xv = bf2f(*(const u16*)(sm + row * 256 + ((col * 2) ^ ((row & 7) << 4))));
                        *(float*)(sm + LDS_U + 8192 + (row * 132 + col) * 4) =
                            pr[mt][nt][i] + bv + xv;
                    }
            }
        }
        __syncthreads();
        if (t < 32) {  // LN1 stats
            float sum = 0.f, sq = 0.f;
            for (int d4 = 0; d4 < 32; ++d4) {
                float4 v4 = *(const float4*)(sm + LDS_U + 8192 + (t * 132 + d4 * 4) * 4);
                sum += v4.x + v4.y + v4.z + v4.w;
                sq += v4.x * v4.x + v4.y * v4.y + v4.z * v4.z + v4.w * v4.w;
            }
            float mu = sum * (1.f / 128.f);
            float var = sq * (1.f / 128.f) - mu * mu;
            *(float*)(sm + LDS_U + 49664 + t * 4) = mu;
            *(float*)(sm + LDS_U + 49664 + 128 + t * 4) = rsqrtf(var + 1e-5f);
        }
        __syncthreads();
        {   // LN1 apply -> h1bf
            float gv = ln1g[e * 128 + dd], bv = ln1b[e * 128 + dd];
#pragma unroll
            for (int i = 0; i < 16; ++i) {
                int n = nb + i;
                float hv = *(const float*)(sm + LDS_U + 8192 + (n * 132 + dd) * 4);
                float mu = *(const float*)(sm + LDS_U + 49664 + n * 4);
                float rs = *(const float*)(sm + LDS_U + 49664 + 128 + n * 4);
                *(u16*)(sm + LDS_U + 33280 + n * 256 + ((dd * 2) ^ ((n & 7) << 4))) =
                    f2bf((hv - mu) * rs * gv + bv);
            }
        }
        __syncthreads();

        // ---- Phase 4: FFN, 8 chunks of 128 hidden
        {
            const int wcb = w * 32;
            f32x4 facc[2][2];
            facc[0][0] = zv; facc[0][1] = zv; facc[1][0] = zv; facc[1][1] = zv;
            for (int c = 0; c < 8; ++c) {
                f32x4 a1acc[2][2];
                a1acc[0][0] = zv; a1acc[0][1] = zv; a1acc[1][0] = zv; a1acc[1][1] = zv;
#pragma unroll
                for (int ks = 0; ks < 4; ++ks) {
                    int kb = (ks * 32 + ke) * 2;
                    bf16x8 a0 = *(const bf16x8*)(sm + LDS_U + 33280 + l16 * 256 + (kb ^ ((l16 & 7) << 4)));
                    bf16x8 a1 = *(const bf16x8*)(sm + LDS_U + 33280 + (16 + l16) * 256 + (kb ^ (((16 + l16) & 7) << 4)));
#pragma unroll
                    for (int nt = 0; nt < 2; ++nt) {
                        int j = c * 128 + wcb + nt * 16 + l16;
                        bf16x8 bb = *(const bf16x8*)(W1 + j * 128 + ks * 32 + ke);
                        a1acc[0][nt] = MFMA(a0, bb, a1acc[0][nt]);
                        a1acc[1][nt] = MFMA(a1, bb, a1acc[1][nt]);
                    }
                }
                __syncthreads();  // prior chunk FFN2 reads done
#pragma unroll
                for (int nt = 0; nt < 2; ++nt) {
                    int jl = wcb + nt * 16 + l16;
                    float bv = b1[e * 1024 + c * 128 + jl];
#pragma unroll
                    for (int mt = 0; mt < 2; ++mt)
#pragma unroll
                        for (int i = 0; i < 4; ++i) {
                            int row = mt * 16 + lk * 4 + i;
                            *(u16*)(sm + LDS_U + 41472 + row * 256 + ((jl * 2) ^ ((row & 7) << 4))) =
                                f2bf(fmaxf(a1acc[mt][nt][i] + bv, 0.f));
                        }
                }
                __syncthreads();  // fchunk ready
#pragma unroll
                for (int ks = 0; ks < 4; ++ks) {
                    int kb = (ks * 32 + ke) * 2;
                    bf16x8 a0 = *(const bf16x8*)(sm + LDS_U + 41472 + l16 * 256 + (kb ^ ((l16 & 7) << 4)));
                    bf16x8 a1 = *(const bf16x8*)(sm + LDS_U + 41472 + (16 + l16) * 256 + (kb ^ (((16 + l16) & 7) << 4)));
#pragma unroll
                    for (int nt = 0; nt < 2; ++nt) {
                        int j = wcb + nt * 16 + l16;
                        bf16x8 bb = *(const bf16x8*)(W2 + j * 1024 + c * 128 + ks * 32 + ke);
                        facc[0][nt] = MFMA(a0, bb, facc[0][nt]);
                        facc[1][nt] = MFMA(a1, bb, facc[1][nt]);
                    }
                }
            }
            // ---- Phase 5: u2 = h1 + f + B2
#pragma unroll
            for (int nt = 0; nt < 2; ++nt) {
                int col = wcb + nt * 16 + l16;
                float bv = b2[e * 128 + col];
#pragma unroll
                for (int mt = 0; mt < 2; ++mt)
#pragma unroll
                    for (int i = 0; i < 4; ++i) {
                        int row = mt * 16 + lk * 4 + i;
                        float h1 = bf2f(*(const u16*)(sm + LDS_U + 33280 + row * 256 +
                                                      ((col * 2) ^ ((row & 7) << 4))));
                        *(float*)(sm + LDS_U + (row * 132 + col) * 4) =
                            facc[mt][nt][i] + bv + h1;
                    }
            }
        }
        __syncthreads();
        if (t < 32) {  // LN2 stats
            float sum = 0.f, sq = 0.f;
            for (int d4 = 0; d4 < 32; ++d4) {
                float4 v4 = *(const float4*)(sm + LDS_U + (t * 132 + d4 * 4) * 4);
                sum += v4.x + v4.y + v4.z + v4.w;
                sq += v4.x * v4.x + v4.y * v4.y + v4.z * v4.z + v4.w * v4.w;
            }
            float mu = sum * (1.f / 128.f);
            float var = sq * (1.f / 128.f) - mu * mu;
            *(float*)(sm + LDS_U + 49664 + t * 4) = mu;
            *(float*)(sm + LDS_U + 49664 + 128 + t * 4) = rsqrtf(var + 1e-5f);
        }
        __syncthreads();
        {   // LN2 apply, gate-accumulate
            float gv = ln2g[e * 128 + dd], bv = ln2b[e * 128 + dd];
#pragma unroll
            for (int i = 0; i < 16; ++i) {
                int n = nb + i;
                float uv = *(const float*)(sm + LDS_U + (n * 132 + dd) * 4);
                float mu = *(const float*)(sm + LDS_U + 49664 + n * 4);
                float rs = *(const float*)(sm + LDS_U + 49664 + 128 + n * 4);
                yacc[i] += g * ((uv - mu) * rs * gv + bv);
            }
        }
    }

#pragma unroll
    for (int i = 0; i < 16; ++i)
        y_bf[b * 4096 + (nb + i) * 128 + dd] = f2bf(yacc[i]);
}

// ---------------- Head1: h_act = relu(y_bf @ hw1^T + hb1), bf16 MFMA --------
__global__ __launch_bounds__(256) void head1_mfma(
    const u16* __restrict__ y_bf, const u16* __restrict__ hw1BF,
    const float* __restrict__ hb1, float* __restrict__ h_act)
{
    const int t = threadIdx.x, w = t >> 6, l = t & 63, l16 = l & 15, lk = l >> 4;
    const int ke = lk * 8;
    const int mb = blockIdx.x * 32, cb = blockIdx.y * 64 + w * 16;
    const f32x4 zv = {0.f, 0.f, 0.f, 0.f};
    f32x4 acc[2]; acc[0] = zv; acc[1] = zv;
    const u16* arow0 = y_bf + (size_t)(mb + l16) * 4096;
    const u16* arow1 = y_bf + (size_t)(mb + 16 + l16) * 4096;
    const u16* brow  = hw1BF + (size_t)(cb + l16) * 4096;
    for (int k0 = 0; k0 < 4096; k0 += 32) {
        bf16x8 a0 = *(const bf16x8*)(arow0 + k0 + ke);
        bf16x8 a1 = *(const bf16x8*)(arow1 + k0 + ke);
        bf16x8 bb = *(const bf16x8*)(brow + k0 + ke);
        acc[0] = MFMA(a0, bb, acc[0]);
        acc[1] = MFMA(a1, bb, acc[1]);
    }
    int col = cb + l16;
    float bv = hb1[col];
#pragma unroll
    for (int mt = 0; mt < 2; ++mt)
#pragma unroll
        for (int i = 0; i < 4; ++i) {
            int row = mb + mt * 16 + lk * 4 + i;
            h_act[(size_t)row * 512 + col] = fmaxf(acc[mt][i] + bv, 0.f);
        }
}

// ---------------- Head2 -----------------------------------------------------
__global__ __launch_bounds__(64) void head2_kernel(
    const float* __restrict__ h_act, const float* __restrict__ w2,
    const float* __restrict__ b2, float* __restrict__ r)
{
    const int b = blockIdx.x, t = threadIdx.x;
    float a0 = 0.f, a1 = 0.f, a2 = 0.f, a3 = 0.f;
    for (int h = t; h < 512; h += 64) {
        float hv = h_act[b * 512 + h];
        a0 += hv * w2[h];
        a1 += hv * w2[512 + h];
        a2 += hv * w2[1024 + h];
        a3 += hv * w2[1536 + h];
    }
#pragma unroll
    for (int off = 32; off; off >>= 1) {
        a0 += __shfl_down(a0, off);
        a1 += __shfl_down(a1, off);
        a2 += __shfl_down(a2, off);
        a3 += __shfl_down(a3, off);
    }
    if (t == 0) {
        r[b * 4 + 0] = a0 + b2[0];
        r[b * 4 + 1] = a1 + b2[1];
        r[b * 4 + 2] = a2 + b2[2];
        r[b * 4 + 3] = a3 + b2[3];
    }
}

// ---------------------------------------------------------------------------
extern "C" void kernel_launch(void* const* d_in, const int* in_sizes, int n_in,
                              void* d_out, int out_size, void* d_ws, size_t ws_size,
                              hipStream_t stream) {
    const float* z    = (const float*)d_in[0];
    const float* a    = (const float*)d_in[1];
    const float* wg   = (const float*)d_in[2];
    const float* w_in = (const float*)d_in[3];
    const float* b_in = (const float*)d_in[4];
    const float* w_o  = (const float*)d_in[5];
    const float* b_o  = (const float*)d_in[6];
    const float* l1g  = (const float*)d_in[7];
    const float* l1b  = (const float*)d_in[8];
    const float* w1   = (const float*)d_in[9];
    const float* b1   = (const float*)d_in[10];
    const float* w2   = (const float*)d_in[11];
    const float* b2   = (const float*)d_in[12];
    const float* l2g  = (const float*)d_in[13];
    const float* l2b  = (const float*)d_in[14];
    const float* hw1  = (const float*)d_in[15];
    const float* hb1  = (const float*)d_in[16];
    const float* hw2  = (const float*)d_in[17];
    const float* hb2  = (const float*)d_in[18];

    float* out = (float*)d_out;
    float* r_out     = out;          // 4096
    float* gates_out = out + 4096;   // 8192
    float* loss_out  = out + 12288;  // 1

    char* W = (char*)d_ws;
    u16*   y_bf  = (u16*)W;                       //  8,388,608 B
    float* h_act = (float*)(W + 8388608);         //  2,097,152 B
    float* lse   = (float*)(W + 10485760);        //      4,096 B
    float* topg  = (float*)(W + 10489856);        //      8,192 B
    int*   topi  = (int*)  (W + 10498048);        //      8,192 B
    u16*   wiBF  = (u16*)  (W + 10506240);        //    786,432 B
    u16*   woBF  = wiBF + 393216;                 //    262,144 B
    u16*   w1BF  = woBF + 131072;                 //  2,097,152 B
    u16*   w2BF  = w1BF + 1048576;                //  2,097,152 B
    u16*   hw1BF = w2BF + 1048576;                //  4,194,304 B  (end ~19.9 MB)

    convert_kernel<<<4608, 256, 0, stream>>>(w_in, w_o, w1, w2, hw1,
                                             wiBF, woBF, w1BF, w2BF, hw1BF);
    router_kernel<<<1024, 256, 0, stream>>>(z, a, wg, gates_out, lse, topi, topg);
    loss_kernel<<<1, 256, 0, stream>>>(gates_out, lse, loss_out);
    expert_kernel<<<1024, 256, 0, stream>>>(z, a, wiBF, b_in, woBF, b_o,
        l1g, l1b, w1BF, b1, w2BF, b2, l2g, l2b, topi, topg, y_bf);
    head1_mfma<<<dim3(32, 8), 256, 0, stream>>>(y_bf, hw1BF, hb1, h_act);
    head2_kernel<<<1024, 64, 0, stream>>>(h_act, hw2, hb2, r_out);
}

// Round 3
// 330.037 us; speedup vs baseline: 4.1455x; 1.4720x over previous
//
#include <hip/hip_runtime.h>
#include <math.h>

// ---------------------------------------------------------------------------
// CenMoERewardModel, grouped-expert bf16-MFMA version.
// B=1024, Na=32, D=128, E=8 top-2, heads=4 (hd=32), F=1024, head 4096->512->4.
// Expert work grouped by expert: 4 (token,slot) entries per block (M=128).
// ---------------------------------------------------------------------------

typedef short bf16x8 __attribute__((ext_vector_type(8)));
typedef float f32x4 __attribute__((ext_vector_type(4)));
typedef unsigned short u16;

#define MFMA(a, b, c) __builtin_amdgcn_mfma_f32_16x16x32_bf16((a), (b), (c), 0, 0, 0)

__device__ __forceinline__ u16 f2bf(float f) {
    unsigned int u = __float_as_uint(f);
    unsigned int r = u + 0x7FFFu + ((u >> 16) & 1u);
    return (u16)(r >> 16);
}
__device__ __forceinline__ float bf2f(u16 s) {
    return __uint_as_float(((unsigned int)s) << 16);
}

// ---------------- weight f32 -> bf16 conversion -----------------------------
__global__ __launch_bounds__(256) void convert_kernel(
    const float* __restrict__ wi, const float* __restrict__ wo,
    const float* __restrict__ w1, const float* __restrict__ w2,
    const float* __restrict__ hw1,
    u16* __restrict__ wiB, u16* __restrict__ woB, u16* __restrict__ w1B,
    u16* __restrict__ w2B, u16* __restrict__ hw1B)
{
    int i4 = blockIdx.x * 256 + threadIdx.x;  // 4608*256 = 1,179,648 exact
    int e = i4 * 4;
    const float* s; u16* d; int off;
    if (e < 393216)       { s = wi;  d = wiB;  off = e; }
    else if (e < 524288)  { s = wo;  d = woB;  off = e - 393216; }
    else if (e < 1572864) { s = w1;  d = w1B;  off = e - 524288; }
    else if (e < 2621440) { s = w2;  d = w2B;  off = e - 1572864; }
    else                  { s = hw1; d = hw1B; off = e - 2621440; }
    float4 v = *(const float4*)(s + off);
    ushort4 o;
    o.x = f2bf(v.x); o.y = f2bf(v.y); o.z = f2bf(v.z); o.w = f2bf(v.w);
    *(ushort4*)(d + off) = o;
}

// ---------------- Router (f32 exact) ---------------------------------------
__global__ __launch_bounds__(256) void router_kernel(
    const float* __restrict__ z, const float* __restrict__ a,
    const float* __restrict__ wg,
    float* __restrict__ gates_out, float* __restrict__ lse_ws,
    int* __restrict__ topi, float* __restrict__ topg)
{
    __shared__ float red[256][9];
    const int b = blockIdx.x, t = threadIdx.x;
    float acc[8];
#pragma unroll
    for (int e = 0; e < 8; ++e) acc[e] = 0.f;
#pragma unroll
    for (int i = 0; i < 16; ++i) {
        int f = i * 256 + t;
        int n = f >> 7, d = f & 127;
        float xv = (d < 96) ? z[(b * 32 + n) * 96 + d]
                            : a[(b * 32 + n) * 32 + d - 96];
        const float* wr = wg + f * 8;
#pragma unroll
        for (int e = 0; e < 8; ++e) acc[e] += xv * wr[e];
    }
#pragma unroll
    for (int e = 0; e < 8; ++e) red[t][e] = acc[e];
    __syncthreads();
    for (int s = 128; s; s >>= 1) {
        if (t < s) {
#pragma unroll
            for (int e = 0; e < 8; ++e) red[t][e] += red[t + s][e];
        }
        __syncthreads();
    }
    if (t == 0) {
        float L[8];
#pragma unroll
        for (int e = 0; e < 8; ++e) L[e] = red[0][e];
        int i0 = 0;
#pragma unroll
        for (int e = 1; e < 8; ++e) if (L[e] > L[i0]) i0 = e;
        int i1 = -1; float v1 = -3.0e38f;
#pragma unroll
        for (int e = 0; e < 8; ++e) if (e != i0 && L[e] > v1) { v1 = L[e]; i1 = e; }
        float e1 = expf(v1 - L[i0]);
        float inv = 1.f / (1.f + e1);
        float g0 = inv, g1 = e1 * inv;
#pragma unroll
        for (int e = 0; e < 8; ++e)
            gates_out[b * 8 + e] = (e == i0) ? g0 : ((e == i1) ? g1 : 0.f);
        float m = L[i0];
        float se = 0.f;
#pragma unroll
        for (int e = 0; e < 8; ++e) se += expf(L[e] - m);
        lse_ws[b] = m + logf(se);
        topi[b * 2 + 0] = i0; topi[b * 2 + 1] = i1;
        topg[b * 2 + 0] = g0; topg[b * 2 + 1] = g1;
    }
}

// ---------------- Balance loss ---------------------------------------------
__global__ __launch_bounds__(256) void loss_kernel(
    const float* __restrict__ gates, const float* __restrict__ lse,
    float* __restrict__ out_loss)
{
    __shared__ float red[17][256];
    const int t = threadIdx.x;
    float imp[8], ld[8]; float ls = 0.f;
#pragma unroll
    for (int e = 0; e < 8; ++e) { imp[e] = 0.f; ld[e] = 0.f; }
    for (int b = t; b < 1024; b += 256) {
#pragma unroll
        for (int e = 0; e < 8; ++e) {
            float g = gates[b * 8 + e];
            imp[e] += g;
            ld[e] += (g > 0.f) ? 1.f : 0.f;
        }
        ls += lse[b];
    }
#pragma unroll
    for (int e = 0; e < 8; ++e) { red[e][t] = imp[e]; red[8 + e][t] = ld[e]; }
    red[16][t] = ls;
    __syncthreads();
    for (int s = 128; s; s >>= 1) {
        if (t < s) {
            for (int q = 0; q < 17; ++q) red[q][t] += red[q][t + s];
        }
        __syncthreads();
    }
    if (t == 0) {
        float cv[2];
        for (int p = 0; p < 2; ++p) {
            float sum = 0.f;
            for (int e = 0; e < 8; ++e) sum += red[p * 8 + e][0];
            float mean = sum * (1.f / 8.f);
            float var = 0.f;
            for (int e = 0; e < 8; ++e) {
                float dd = red[p * 8 + e][0] - mean;
                var += dd * dd;
            }
            var *= (1.f / 7.f);
            cv[p] = var / (mean * mean + 1e-10f);
        }
        out_loss[0] = cv[0] + cv[1] + red[16][0] * (1.f / 1024.f);
    }
}

// ---------------- Build per-expert entry lists + tile metadata --------------
// ent[e][i] = token*2 + slot ; meta[0] = n_tiles ; meta[1+2t]=expert, meta[2+2t]=base
__global__ __launch_bounds__(1024) void build_kernel(
    const int* __restrict__ topi, int* __restrict__ cnts,
    int* __restrict__ ent, int* __restrict__ meta)
{
    __shared__ int sc_[8];
    __shared__ int toff[9];
    const int t = threadIdx.x;
    if (t < 8) sc_[t] = 0;
    __syncthreads();
    int e0 = topi[t * 2], e1 = topi[t * 2 + 1];
    int p0 = atomicAdd(&sc_[e0], 1);
    ent[e0 * 2048 + p0] = t * 2;
    int p1 = atomicAdd(&sc_[e1], 1);
    ent[e1 * 2048 + p1] = t * 2 + 1;
    __syncthreads();
    if (t == 0) {
        int off = 0;
        for (int e = 0; e < 8; ++e) { toff[e] = off; off += (sc_[e] + 3) >> 2; }
        toff[8] = off;
        meta[0] = off;
    }
    __syncthreads();
    if (t < 8) {
        cnts[t] = sc_[t];
        int ntl = (sc_[t] + 3) >> 2, o = toff[t];
        for (int j = 0; j < ntl; ++j) {
            meta[1 + 2 * (o + j)] = t;
            meta[2 + 2 * (o + j)] = j * 4;
        }
    }
}

// ---------------- Grouped expert kernel ------------------------------------
// LDS regions (bytes), all tiles [128 rows][256B] with swizzle ((col*2)^((row&7)<<4)):
//   X  @0       32KB  input rows (residual)
//   Q  @32768   32KB  q  -> attn output O -> proj A-operand
//   K  @65536   32KB  k  -> h1 (LN1 out, FFN A-operand)
//   VT @98304   32KB  v transposed -> FFN F chunk -> final y tile
//   P  @131072  16KB  per-wave softmax scratch (2KB each)
//   ps @147456 2KB, pq @149504 2KB, mu @151552 512B, rs @152064 512B
#define SM_X  0
#define SM_Q  32768
#define SM_K  65536
#define SM_VT 98304
#define SM_P  131072
#define SM_PS 147456
#define SM_PQ 149504
#define SM_MU 151552
#define SM_RS 152064
#define SM_TOTAL 152576
#define NTILES 520

__global__ __launch_bounds__(512, 2) void expert_group_kernel(
    const float* __restrict__ z, const float* __restrict__ a,
    const u16* __restrict__ wiBF, const float* __restrict__ b_in,
    const u16* __restrict__ woBF, const float* __restrict__ b_out,
    const float* __restrict__ ln1g, const float* __restrict__ ln1b,
    const u16* __restrict__ w1BF, const float* __restrict__ b1,
    const u16* __restrict__ w2BF, const float* __restrict__ b2,
    const float* __restrict__ ln2g, const float* __restrict__ ln2b,
    const float* __restrict__ topg, const int* __restrict__ cnts,
    const int* __restrict__ meta, const int* __restrict__ ent,
    u16* __restrict__ ybf)   // [2][1024][4096]
{
    __shared__ __align__(16) char sm[SM_TOTAL];
    const int n_tiles = meta[0];
    const int bid = blockIdx.x;
    if (bid >= n_tiles) return;
    const int e = meta[1 + 2 * bid], base = meta[2 + 2 * bid];
    const int cnt = cnts[e];

    const int t = threadIdx.x;
    const int w = t >> 6, l = t & 63, l16 = l & 15, lk = l >> 4;
    const int ke = lk * 8;           // k-element base within a 32-wide k-step
    const int wr = w >> 2, wc = w & 3;  // 2M x 4N wave grid for M=128 GEMMs
    const f32x4 zv = {0.f, 0.f, 0.f, 0.f};

    // decode 4 entries
    int bs[4], valid[4]; float gg[4];
#pragma unroll
    for (int i = 0; i < 4; ++i) {
        int gi = base + i;
        int idx = (gi < cnt) ? gi : (cnt - 1);
        int code = ent[e * 2048 + idx];
        valid[i] = (gi < cnt);
        bs[i] = code;
        gg[i] = topg[code];
    }

    // ---- gather X = concat(z,a) for 4 tokens -> SM_X (bf16, swz)
    {
        const int grow = t >> 4;            // 0..31
        const int gcol = (t & 15) * 8;      // 0..120
#pragma unroll
        for (int i = 0; i < 4; ++i) {
            int b_ = bs[i] >> 1;
            float v[8];
            if (gcol < 96) {
                const float* zp = z + ((size_t)b_ * 32 + grow) * 96 + gcol;
                float4 p0 = *(const float4*)zp, p1 = *(const float4*)(zp + 4);
                v[0] = p0.x; v[1] = p0.y; v[2] = p0.z; v[3] = p0.w;
                v[4] = p1.x; v[5] = p1.y; v[6] = p1.z; v[7] = p1.w;
            } else {
                const float* ap = a + ((size_t)b_ * 32 + grow) * 32 + (gcol - 96);
                float4 p0 = *(const float4*)ap, p1 = *(const float4*)(ap + 4);
                v[0] = p0.x; v[1] = p0.y; v[2] = p0.z; v[3] = p0.w;
                v[4] = p1.x; v[5] = p1.y; v[6] = p1.z; v[7] = p1.w;
            }
            bf16x8 pk;
#pragma unroll
            for (int j = 0; j < 8; ++j) pk[j] = (short)f2bf(v[j]);
            int row = i * 32 + grow;
            *(bf16x8*)(sm + SM_X + row * 256 + ((gcol * 2) ^ ((row & 7) << 4))) = pk;
        }
    }
    __syncthreads();

    // ---- Phase 1: qkv GEMM  M=128 N=384 K=128. wave: rows wr*64.., cols wc*96..
    {
        f32x4 acc[4][6];
#pragma unroll
        for (int m = 0; m < 4; ++m)
#pragma unroll
            for (int q = 0; q < 6; ++q) acc[m][q] = zv;
#pragma unroll
        for (int ks = 0; ks < 4; ++ks) {
            int kb = (ks * 32 + ke) * 2;
            bf16x8 af[4];
#pragma unroll
            for (int m = 0; m < 4; ++m) {
                int R = wr * 64 + m * 16 + l16;
                af[m] = *(const bf16x8*)(sm + SM_X + R * 256 + (kb ^ ((R & 7) << 4)));
            }
#pragma unroll
            for (int q = 0; q < 6; ++q) {
                int j = wc * 96 + q * 16 + l16;
                bf16x8 bb = *(const bf16x8*)(wiBF + e * 49152 + j * 128 + ks * 32 + ke);
#pragma unroll
                for (int m = 0; m < 4; ++m) acc[m][q] = MFMA(af[m], bb, acc[m][q]);
            }
        }
#pragma unroll
        for (int q = 0; q < 6; ++q) {
            int C = wc * 96 + q * 16 + l16;
            float bj = b_in[e * 384 + C];
#pragma unroll
            for (int m = 0; m < 4; ++m)
#pragma unroll
                for (int i = 0; i < 4; ++i) {
                    int R = wr * 64 + m * 16 + lk * 4 + i;
                    u16 val = f2bf(acc[m][q][i] + bj);
                    if (C < 128) {
                        *(u16*)(sm + SM_Q + R * 256 + ((C * 2) ^ ((R & 7) << 4))) = val;
                    } else if (C < 256) {
                        int c2 = C - 128;
                        *(u16*)(sm + SM_K + R * 256 + ((c2 * 2) ^ ((R & 7) << 4))) = val;
                    } else {
                        int rv = C - 256;  // VT[rv][R]
                        *(u16*)(sm + SM_VT + rv * 256 + ((R * 2) ^ ((rv & 7) << 4))) = val;
                    }
                }
        }
    }
    __syncthreads();

    // ---- Phase 2: attention. wave w -> token tok = w>>1, heads h2,h2+1
    f32x4 Ofrag[2][2][2];
    {
        const int tok = w >> 1;
        const int h2 = (w & 1) * 2;
        const float scale = 0.17677669529663687f;  // 1/sqrt(32)
#pragma unroll
        for (int p = 0; p < 2; ++p) {
            const int hb = (h2 + p) * 32;
            bf16x8 qa[2], kb2[2];
#pragma unroll
            for (int mt = 0; mt < 2; ++mt) {
                int R = tok * 32 + mt * 16 + l16;
                qa[mt] = *(const bf16x8*)(sm + SM_Q + R * 256 + (((hb + ke) * 2) ^ ((R & 7) << 4)));
                kb2[mt] = *(const bf16x8*)(sm + SM_K + R * 256 + (((hb + ke) * 2) ^ ((R & 7) << 4)));
            }
            f32x4 sc[2][2];
            sc[0][0] = MFMA(qa[0], kb2[0], zv); sc[0][1] = MFMA(qa[0], kb2[1], zv);
            sc[1][0] = MFMA(qa[1], kb2[0], zv); sc[1][1] = MFMA(qa[1], kb2[1], zv);
            // softmax over 32 keys per query row
#pragma unroll
            for (int mt = 0; mt < 2; ++mt)
#pragma unroll
                for (int i = 0; i < 4; ++i) {
                    float v0 = sc[mt][0][i] * scale, v1 = sc[mt][1][i] * scale;
                    float m = fmaxf(v0, v1);
                    m = fmaxf(m, __shfl_xor(m, 1)); m = fmaxf(m, __shfl_xor(m, 2));
                    m = fmaxf(m, __shfl_xor(m, 4)); m = fmaxf(m, __shfl_xor(m, 8));
                    float e0 = __expf(v0 - m), e1 = __expf(v1 - m);
                    float ssum = e0 + e1;
                    ssum += __shfl_xor(ssum, 1); ssum += __shfl_xor(ssum, 2);
                    ssum += __shfl_xor(ssum, 4); ssum += __shfl_xor(ssum, 8);
                    float inv = 1.f / ssum;
                    int row = mt * 16 + lk * 4 + i;
                    char* pb = sm + SM_P + w * 2048 + row * 64;
                    int sw = (row & 3) << 4;
                    *(u16*)(pb + ((l16 * 2) ^ sw)) = f2bf(e0 * inv);
                    *(u16*)(pb + (((16 + l16) * 2) ^ sw)) = f2bf(e1 * inv);
                }
            // PV: O = P @ V  (K=32 keys, single k-step)
            bf16x8 pa[2];
#pragma unroll
            for (int mt = 0; mt < 2; ++mt) {
                int row = mt * 16 + l16;
                pa[mt] = *(const bf16x8*)(sm + SM_P + w * 2048 + row * 64 +
                                          ((ke * 2) ^ ((row & 3) << 4)));
            }
#pragma unroll
            for (int nt = 0; nt < 2; ++nt) {
                int rv = hb + nt * 16 + l16;  // VT row = v column
                bf16x8 vb = *(const bf16x8*)(sm + SM_VT + rv * 256 +
                                             (((tok * 32 + ke) * 2) ^ ((rv & 7) << 4)));
                Ofrag[p][0][nt] = MFMA(pa[0], vb, zv);
                Ofrag[p][1][nt] = MFMA(pa[1], vb, zv);
            }
        }
        // write O into Q region (cols this wave owned as Q: safe, no barrier needed
        // before writes; disjoint from other waves' reads)
#pragma unroll
        for (int p = 0; p < 2; ++p)
#pragma unroll
            for (int mt = 0; mt < 2; ++mt)
#pragma unroll
                for (int nt = 0; nt < 2; ++nt)
#pragma unroll
                    for (int i = 0; i < 4; ++i) {
                        int R = tok * 32 + mt * 16 + lk * 4 + i;
                        int C = (h2 + p) * 32 + nt * 16 + l16;
                        *(u16*)(sm + SM_Q + R * 256 + ((C * 2) ^ ((R & 7) << 4))) =
                            f2bf(Ofrag[p][mt][nt][i]);
                    }
    }
    // prefetch proj weight frags before barrier
    bf16x8 wof[2][4];
#pragma unroll
    for (int nt = 0; nt < 2; ++nt)
#pragma unroll
        for (int ks = 0; ks < 4; ++ks) {
            int j = wc * 32 + nt * 16 + l16;
            wof[nt][ks] = *(const bf16x8*)(woBF + e * 16384 + j * 128 + ks * 32 + ke);
        }
    __syncthreads();

    // ---- Phase 3: proj GEMM M=128 N=128 K=128 ; u1 = x + o@wo^T + bo ; LN1
    {
        f32x4 pr[4][2];
#pragma unroll
        for (int m = 0; m < 4; ++m) { pr[m][0] = zv; pr[m][1] = zv; }
#pragma unroll
        for (int ks = 0; ks < 4; ++ks) {
            int kb = (ks * 32 + ke) * 2;
            bf16x8 af[4];
#pragma unroll
            for (int m = 0; m < 4; ++m) {
                int R = wr * 64 + m * 16 + l16;
                af[m] = *(const bf16x8*)(sm + SM_Q + R * 256 + (kb ^ ((R & 7) << 4)));
            }
#pragma unroll
            for (int m = 0; m < 4; ++m) {
                pr[m][0] = MFMA(af[m], wof[0][ks], pr[m][0]);
                pr[m][1] = MFMA(af[m], wof[1][ks], pr[m][1]);
            }
        }
        float bo0 = b_out[e * 128 + wc * 32 + l16];
        float bo1 = b_out[e * 128 + wc * 32 + 16 + l16];
        // u1 = pr + bo + x ; write to H (=SM_K region), stats partials
#pragma unroll
        for (int m = 0; m < 4; ++m) {
#pragma unroll
            for (int i = 0; i < 4; ++i) {
                int R = wr * 64 + m * 16 + lk * 4 + i;
                float u0, u1v;
                {
                    int C0 = wc * 32 + l16, C1 = C0 + 16;
                    float x0 = bf2f(*(const u16*)(sm + SM_X + R * 256 + ((C0 * 2) ^ ((R & 7) << 4))));
                    float x1 = bf2f(*(const u16*)(sm + SM_X + R * 256 + ((C1 * 2) ^ ((R & 7) << 4))));
                    u0 = pr[m][0][i] + bo0 + x0;
                    u1v = pr[m][1][i] + bo1 + x1;
                    *(u16*)(sm + SM_K + R * 256 + ((C0 * 2) ^ ((R & 7) << 4))) = f2bf(u0);
                    *(u16*)(sm + SM_K + R * 256 + ((C1 * 2) ^ ((R & 7) << 4))) = f2bf(u1v);
                }
                float s = u0 + u1v;
                float q = u0 * u0 + u1v * u1v;
                s += __shfl_xor(s, 1); q += __shfl_xor(q, 1);
                s += __shfl_xor(s, 2); q += __shfl_xor(q, 2);
                s += __shfl_xor(s, 4); q += __shfl_xor(q, 4);
                s += __shfl_xor(s, 8); q += __shfl_xor(q, 8);
                if (l16 == 0) {
                    *(float*)(sm + SM_PS + (R * 4 + wc) * 4) = s;
                    *(float*)(sm + SM_PQ + (R * 4 + wc) * 4) = q;
                }
            }
        }
    }
    __syncthreads();
    if (t < 128) {
        float s = 0.f, q = 0.f;
#pragma unroll
        for (int c = 0; c < 4; ++c) {
            s += *(const float*)(sm + SM_PS + (t * 4 + c) * 4);
            q += *(const float*)(sm + SM_PQ + (t * 4 + c) * 4);
        }
        float mu = s * (1.f / 128.f);
        float var = q * (1.f / 128.f) - mu * mu;
        *(float*)(sm + SM_MU + t * 4) = mu;
        *(float*)(sm + SM_RS + t * 4) = rsqrtf(var + 1e-5f);
    }
    __syncthreads();
    {   // LN1 apply in place over H region
        int r_ = t >> 2, c0 = (t & 3) * 32;
        float mu_ = *(const float*)(sm + SM_MU + r_ * 4);
        float rs_ = *(const float*)(sm + SM_RS + r_ * 4);
#pragma unroll
        for (int j4 = 0; j4 < 4; ++j4) {
            int cb = c0 + j4 * 8;
            bf16x8* p = (bf16x8*)(sm + SM_K + r_ * 256 + ((cb * 2) ^ ((r_ & 7) << 4)));
            bf16x8 vch = *p;
#pragma unroll
            for (int jj = 0; jj < 8; ++jj) {
                int c = cb + jj;
                float f = (bf2f((u16)vch[jj]) - mu_) * rs_ * ln1g[e * 128 + c] + ln1b[e * 128 + c];
                vch[jj] = (short)f2bf(f);
            }
            *p = vch;
        }
    }
    __syncthreads();

    // ---- Phase 4: FFN, 8 chunks of 128 hidden cols, weight frags prefetched
    f32x4 facc[4][2];
#pragma unroll
    for (int m = 0; m < 4; ++m) { facc[m][0] = zv; facc[m][1] = zv; }
    {
        bf16x8 w1f[2][4], w2f[2][4];
#pragma unroll
        for (int nt = 0; nt < 2; ++nt)
#pragma unroll
            for (int ks = 0; ks < 4; ++ks) {
                int j = wc * 32 + nt * 16 + l16;  // chunk 0
                w1f[nt][ks] = *(const bf16x8*)(w1BF + e * 131072 + j * 128 + ks * 32 + ke);
            }
        for (int c = 0; c < 8; ++c) {
            // prefetch W2 frags for this chunk (in flight during GEMM1)
#pragma unroll
            for (int nt = 0; nt < 2; ++nt)
#pragma unroll
                for (int ks = 0; ks < 4; ++ks) {
                    int j = wc * 32 + nt * 16 + l16;
                    w2f[nt][ks] = *(const bf16x8*)(w2BF + e * 131072 + j * 1024 +
                                                   c * 128 + ks * 32 + ke);
                }
            // GEMM1: a1 = h1 @ W1_chunk^T
            f32x4 a1[4][2];
#pragma unroll
            for (int m = 0; m < 4; ++m) { a1[m][0] = zv; a1[m][1] = zv; }
#pragma unroll
            for (int ks = 0; ks < 4; ++ks) {
                int kb = (ks * 32 + ke) * 2;
                bf16x8 af[4];
#pragma unroll
                for (int m = 0; m < 4; ++m) {
                    int R = wr * 64 + m * 16 + l16;
                    af[m] = *(const bf16x8*)(sm + SM_K + R * 256 + (kb ^ ((R & 7) << 4)));
                }
#pragma unroll
                for (int m = 0; m < 4; ++m) {
                    a1[m][0] = MFMA(af[m], w1f[0][ks], a1[m][0]);
                    a1[m][1] = MFMA(af[m], w1f[1][ks], a1[m][1]);
                }
            }
            __syncthreads();  // previous chunk's F reads complete
            float b10 = b1[e * 1024 + c * 128 + wc * 32 + l16];
            float b11 = b1[e * 1024 + c * 128 + wc * 32 + 16 + l16];
#pragma unroll
            for (int m = 0; m < 4; ++m)
#pragma unroll
                for (int nt = 0; nt < 2; ++nt)
#pragma unroll
                    for (int i = 0; i < 4; ++i) {
                        int R = wr * 64 + m * 16 + lk * 4 + i;
                        int C = wc * 32 + nt * 16 + l16;
                        *(u16*)(sm + SM_VT + R * 256 + ((C * 2) ^ ((R & 7) << 4))) =
                            f2bf(fmaxf(a1[m][nt][i] + (nt ? b11 : b10), 0.f));
                    }
            // prefetch W1 frags for next chunk (in flight during GEMM2)
            if (c < 7) {
#pragma unroll
                for (int nt = 0; nt < 2; ++nt)
#pragma unroll
                    for (int ks = 0; ks < 4; ++ks) {
                        int j = (c + 1) * 128 + wc * 32 + nt * 16 + l16;
                        w1f[nt][ks] = *(const bf16x8*)(w1BF + e * 131072 + j * 128 + ks * 32 + ke);
                    }
            }
            __syncthreads();  // F ready
            // GEMM2: facc += F @ W2_chunk^T
#pragma unroll
            for (int ks = 0; ks < 4; ++ks) {
                int kb = (ks * 32 + ke) * 2;
                bf16x8 af[4];
#pragma unroll
                for (int m = 0; m < 4; ++m) {
                    int R = wr * 64 + m * 16 + l16;
                    af[m] = *(const bf16x8*)(sm + SM_VT + R * 256 + (kb ^ ((R & 7) << 4)));
                }
#pragma unroll
                for (int m = 0; m < 4; ++m) {
                    facc[m][0] = MFMA(af[m], w2f[0][ks], facc[m][0]);
                    facc[m][1] = MFMA(af[m], w2f[1][ks], facc[m][1]);
                }
            }
        }
    }

    // ---- Phase 5: u2 = h1 + f + b2 ; LN2 ; gate ; write
    {
        float b20 = b2[e * 128 + wc * 32 + l16];
        float b21 = b2[e * 128 + wc * 32 + 16 + l16];
        float u2[4][2][4];
#pragma unroll
        for (int m = 0; m < 4; ++m)
#pragma unroll
            for (int i = 0; i < 4; ++i) {
                int R = wr * 64 + m * 16 + lk * 4 + i;
                int C0 = wc * 32 + l16, C1 = C0 + 16;
                float h0 = bf2f(*(const u16*)(sm + SM_K + R * 256 + ((C0 * 2) ^ ((R & 7) << 4))));
                float h1v = bf2f(*(const u16*)(sm + SM_K + R * 256 + ((C1 * 2) ^ ((R & 7) << 4))));
                u2[m][0][i] = facc[m][0][i] + b20 + h0;
                u2[m][1][i] = facc[m][1][i] + b21 + h1v;
                float s = u2[m][0][i] + u2[m][1][i];
                float q = u2[m][0][i] * u2[m][0][i] + u2[m][1][i] * u2[m][1][i];
                s += __shfl_xor(s, 1); q += __shfl_xor(q, 1);
                s += __shfl_xor(s, 2); q += __shfl_xor(q, 2);
                s += __shfl_xor(s, 4); q += __shfl_xor(q, 4);
                s += __shfl_xor(s, 8); q += __shfl_xor(q, 8);
                if (l16 == 0) {
                    *(float*)(sm + SM_PS + (R * 4 + wc) * 4) = s;
                    *(float*)(sm + SM_PQ + (R * 4 + wc) * 4) = q;
                }
            }
        __syncthreads();
        if (t < 128) {
            float s = 0.f, q = 0.f;
#pragma unroll
            for (int c = 0; c < 4; ++c) {
                s += *(const float*)(sm + SM_PS + (t * 4 + c) * 4);
                q += *(const float*)(sm + SM_PQ + (t * 4 + c) * 4);
            }
            float mu = s * (1.f / 128.f);
            float var = q * (1.f / 128.f) - mu * mu;
            *(float*)(sm + SM_MU + t * 4) = mu;
            *(float*)(sm + SM_RS + t * 4) = rsqrtf(var + 1e-5f);
        }
        __syncthreads();
        float g20 = ln2g[e * 128 + wc * 32 + l16];
        float g21 = ln2g[e * 128 + wc * 32 + 16 + l16];
        float e20 = ln2b[e * 128 + wc * 32 + l16];
        float e21 = ln2b[e * 128 + wc * 32 + 16 + l16];
#pragma unroll
        for (int m = 0; m < 4; ++m) {
            float gm = gg[wr * 2 + (m >> 1)];
#pragma unroll
            for (int i = 0; i < 4; ++i) {
                int R = wr * 64 + m * 16 + lk * 4 + i;
                float mu_ = *(const float*)(sm + SM_MU + R * 4);
                float rs_ = *(const float*)(sm + SM_RS + R * 4);
                int C0 = wc * 32 + l16, C1 = C0 + 16;
                float v0 = gm * ((u2[m][0][i] - mu_) * rs_ * g20 + e20);
                float v1 = gm * ((u2[m][1][i] - mu_) * rs_ * g21 + e21);
                *(u16*)(sm + SM_VT + R * 256 + ((C0 * 2) ^ ((R & 7) << 4))) = f2bf(v0);
                *(u16*)(sm + SM_VT + R * 256 + ((C1 * 2) ^ ((R & 7) << 4))) = f2bf(v1);
            }
        }
    }
    __syncthreads();
    // coalesced global write from SM_VT
    {
        int r_ = t >> 2, c0 = (t & 3) * 32;
        int ei = r_ >> 5;
        if (valid[ei]) {
            int code = bs[ei];
            int b_ = code >> 1, s_ = code & 1;
            u16* dst = ybf + ((size_t)(s_ * 1024 + b_)) * 4096 + (r_ & 31) * 128 + c0;
#pragma unroll
            for (int j4 = 0; j4 < 4; ++j4) {
                *(bf16x8*)(dst + j4 * 8) =
                    *(const bf16x8*)(sm + SM_VT + r_ * 256 + (((c0 + j4 * 8) * 2) ^ ((r_ & 7) << 4)));
            }
        }
    }
}

// ---------------- Combine: y = slot0 + slot1 (into slot0) ------------------
__global__ __launch_bounds__(256) void combine_kernel(
    u16* __restrict__ y0, const u16* __restrict__ y1)
{
    int i = (blockIdx.x * 256 + threadIdx.x) * 8;
    bf16x8 a = *(const bf16x8*)(y0 + i);
    bf16x8 b = *(const bf16x8*)(y1 + i);
    bf16x8 o;
#pragma unroll
    for (int j = 0; j < 8; ++j)
        o[j] = (short)f2bf(bf2f((u16)a[j]) + bf2f((u16)b[j]));
    *(bf16x8*)(y0 + i) = o;
}

// ---------------- Head1: h_act = relu(y @ hw1^T + hb1), bf16 MFMA -----------
__global__ __launch_bounds__(256) void head1_mfma(
    const u16* __restrict__ y_bf, const u16* __restrict__ hw1BF,
    const float* __restrict__ hb1, float* __restrict__ h_act)
{
    const int t = threadIdx.x, w = t >> 6, l = t & 63, l16 = l & 15, lk = l >> 4;
    const int ke = lk * 8;
    const int mb = blockIdx.x * 32, cb = blockIdx.y * 64 + w * 16;
    const f32x4 zv = {0.f, 0.f, 0.f, 0.f};
    f32x4 acc[2]; acc[0] = zv; acc[1] = zv;
    const u16* arow0 = y_bf + (size_t)(mb + l16) * 4096;
    const u16* arow1 = y_bf + (size_t)(mb + 16 + l16) * 4096;
    const u16* brow  = hw1BF + (size_t)(cb + l16) * 4096;
    for (int k0 = 0; k0 < 4096; k0 += 32) {
        bf16x8 a0 = *(const bf16x8*)(arow0 + k0 + ke);
        bf16x8 a1 = *(const bf16x8*)(arow1 + k0 + ke);
        bf16x8 bb = *(const bf16x8*)(brow + k0 + ke);
        acc[0] = MFMA(a0, bb, acc[0]);
        acc[1] = MFMA(a1, bb, acc[1]);
    }
    int col = cb + l16;
    float bv = hb1[col];
#pragma unroll
    for (int mt = 0; mt < 2; ++mt)
#pragma unroll
        for (int i = 0; i < 4; ++i) {
            int row = mb + mt * 16 + lk * 4 + i;
            h_act[(size_t)row * 512 + col] = fmaxf(acc[mt][i] + bv, 0.f);
        }
}

// ---------------- Head2 -----------------------------------------------------
__global__ __launch_bounds__(64) void head2_kernel(
    const float* __restrict__ h_act, const float* __restrict__ w2,
    const float* __restrict__ b2, float* __restrict__ r)
{
    const int b = blockIdx.x, t = threadIdx.x;
    float a0 = 0.f, a1 = 0.f, a2 = 0.f, a3 = 0.f;
    for (int h = t; h < 512; h += 64) {
        float hv = h_act[b * 512 + h];
        a0 += hv * w2[h];
        a1 += hv * w2[512 + h];
        a2 += hv * w2[1024 + h];
        a3 += hv * w2[1536 + h];
    }
#pragma unroll
    for (int off = 32; off; off >>= 1) {
        a0 += __shfl_down(a0, off);
        a1 += __shfl_down(a1, off);
        a2 += __shfl_down(a2, off);
        a3 += __shfl_down(a3, off);
    }
    if (t == 0) {
        r[b * 4 + 0] = a0 + b2[0];
        r[b * 4 + 1] = a1 + b2[1];
        r[b * 4 + 2] = a2 + b2[2];
        r[b * 4 + 3] = a3 + b2[3];
    }
}

// ---------------------------------------------------------------------------
extern "C" void kernel_launch(void* const* d_in, const int* in_sizes, int n_in,
                              void* d_out, int out_size, void* d_ws, size_t ws_size,
                              hipStream_t stream) {
    const float* z    = (const float*)d_in[0];
    const float* a    = (const float*)d_in[1];
    const float* wg   = (const float*)d_in[2];
    const float* w_in = (const float*)d_in[3];
    const float* b_in = (const float*)d_in[4];
    const float* w_o  = (const float*)d_in[5];
    const float* b_o  = (const float*)d_in[6];
    const float* l1g  = (const float*)d_in[7];
    const float* l1b  = (const float*)d_in[8];
    const float* w1   = (const float*)d_in[9];
    const float* b1   = (const float*)d_in[10];
    const float* w2   = (const float*)d_in[11];
    const float* b2   = (const float*)d_in[12];
    const float* l2g  = (const float*)d_in[13];
    const float* l2b  = (const float*)d_in[14];
    const float* hw1  = (const float*)d_in[15];
    const float* hb1  = (const float*)d_in[16];
    const float* hw2  = (const float*)d_in[17];
    const float* hb2  = (const float*)d_in[18];

    float* out = (float*)d_out;
    float* r_out     = out;          // 4096
    float* gates_out = out + 4096;   // 8192
    float* loss_out  = out + 12288;  // 1

    char* W = (char*)d_ws;
    u16*   wiBF  = (u16*)(W + 0);          //   786,432 B
    u16*   woBF  = (u16*)(W + 786432);     //   262,144 B
    u16*   w1BF  = (u16*)(W + 1048576);    // 2,097,152 B
    u16*   w2BF  = (u16*)(W + 3145728);    // 2,097,152 B
    u16*   hw1BF = (u16*)(W + 5242880);    // 4,194,304 B
    u16*   ybf   = (u16*)(W + 9437184);    // 16,777,216 B (2 slots)
    float* h_act = (float*)(W + 26214400); // 2,097,152 B
    float* lse   = (float*)(W + 28311552); // 4,096 B
    float* topg  = (float*)(W + 28315648); // 8,192 B
    int*   topi  = (int*)  (W + 28323840); // 8,192 B
    int*   cnts  = (int*)  (W + 28332032); // 32 B
    int*   meta  = (int*)  (W + 28332064); // 4,164 B
    int*   ent   = (int*)  (W + 28336256); // 65,536 B  (end ~28.4 MB)

    convert_kernel<<<4608, 256, 0, stream>>>(w_in, w_o, w1, w2, hw1,
                                             wiBF, woBF, w1BF, w2BF, hw1BF);
    router_kernel<<<1024, 256, 0, stream>>>(z, a, wg, gates_out, lse, topi, topg);
    loss_kernel<<<1, 256, 0, stream>>>(gates_out, lse, loss_out);
    build_kernel<<<1, 1024, 0, stream>>>(topi, cnts, ent, meta);
    expert_group_kernel<<<NTILES, 512, 0, stream>>>(z, a, wiBF, b_in, woBF, b_o,
        l1g, l1b, w1BF, b1, w2BF, b2, l2g, l2b, topg, cnts, meta, ent, ybf);
    combine_kernel<<<2048, 256, 0, stream>>>(ybf, ybf + 4194304);
    head1_mfma<<<dim3(32, 8), 256, 0, stream>>>(ybf, hw1BF, hb1, h_act);
    head2_kernel<<<1024, 64, 0, stream>>>(h_act, hw2, hb2, r_out);
}